// Round 3
// baseline (193.909 us; speedup 1.0000x reference)
//
#include <hip/hip_runtime.h>

#define D 128
#define LDA 136     // bf16 elems per LDS row (+8 pad)
#define BCAP 64     // bucket capacity per dst (max degree ~35 for this data)
#define CSTRIDE 16  // counts padded: 1 counter per 64B line
#define OVCAP 65536 // overflow list capacity (correct fallback, empty in practice)

typedef __attribute__((ext_vector_type(8))) short bf16x8;
typedef __attribute__((ext_vector_type(4))) float f32x4;
typedef __attribute__((ext_vector_type(4))) unsigned int u32x4;

static __device__ __forceinline__ unsigned short f2bf(float f) {
    unsigned u = __float_as_uint(f);
    unsigned r = 0x7fffu + ((u >> 16) & 1u);   // round-to-nearest-even
    return (unsigned short)((u + r) >> 16);
}
static __device__ __forceinline__ float bflo(unsigned u) { return __uint_as_float(u << 16); }
static __device__ __forceinline__ float bfhi(unsigned u) { return __uint_as_float(u & 0xffff0000u); }

// ---------------------------------------------------------------------------
// prep: thread i handles edge i (if i<E) INTERLEAVED with convert chunk i.
// Scattered-op budget is structural: 600K atomics + 600K scattered stores at
// ~22ns marginal each at the coherence point (round-1/2 measurements: nt
// hints and line-colocation both WRITE_SIZE-invariant). Leave as is.
// ---------------------------------------------------------------------------
template<bool BF16H>
__global__ __launch_bounds__(256) void prep_kernel(
    const float* __restrict__ H, unsigned* __restrict__ Hb, int nh8,
    const float* __restrict__ W, unsigned short* __restrict__ Wt,
    const int* __restrict__ esrc, const int* __restrict__ edst, int E,
    int* __restrict__ counts, int* __restrict__ buckets,
    int* __restrict__ ovcnt, int* __restrict__ ovd, int* __restrict__ ovs)
{
    int i = blockIdx.x * 256 + threadIdx.x;

    // --- edge: load + atomic issued first ---
    int d = 0, s = 0, c = 0;
    bool hasE = (i < E);
    if (hasE) {
        d = __builtin_nontemporal_load(edst + i);
        s = __builtin_nontemporal_load(esrc + i);
    }
    if (hasE) c = atomicAdd(&counts[(size_t)d * CSTRIDE], 1);

    // --- convert (independent; its loads queue behind the atomic) ---
    if (BF16H && i < nh8) {
        const f32x4* h4 = (const f32x4*)H;
        f32x4 v0 = __builtin_nontemporal_load(h4 + (size_t)i * 2);
        f32x4 v1 = __builtin_nontemporal_load(h4 + (size_t)i * 2 + 1);
        u32x4 o;
        o.x = (unsigned)f2bf(v0.x) | ((unsigned)f2bf(v0.y) << 16);
        o.y = (unsigned)f2bf(v0.z) | ((unsigned)f2bf(v0.w) << 16);
        o.z = (unsigned)f2bf(v1.x) | ((unsigned)f2bf(v1.y) << 16);
        o.w = (unsigned)f2bf(v1.z) | ((unsigned)f2bf(v1.w) << 16);
        __builtin_nontemporal_store(o, (u32x4*)Hb + i);
    } else {
        int j = i - nh8;
        if (j >= 0 && j < 16384) {         // Wt[n][k] = bf16(W[k][n])
            int k = j >> 7, n = j & 127;
            float wv = __builtin_nontemporal_load(W + j);
            Wt[n * 128 + k] = f2bf(wv);
        }
    }

    // --- edge: place into bucket (atomic result long since landed) ---
    if (hasE) {
        if (c < BCAP) {
            buckets[(size_t)d * BCAP + c] = s;
        } else {                            // correct overflow path (empty here)
            int o = atomicAdd(ovcnt, 1);
            if (o < OVCAP) { ovd[o] = d; ovs[o] = s; }
        }
    }
}

// ---------------------------------------------------------------------------
// FUSED aggregate + GEMM + finalize (bf16 path). Each block owns 64 dst
// rows; each of the 4 waves aggregates 16 rows (software-pipelined bucket
// loads, 8 gather rows in flight) directly into the LDS A-tile, then the
// verified MFMA epilogue runs: out = relu((A @ W)/max(deg,1) + (deg>0?b:0)).
// Saves the aggb global round-trip (25.6MB) + one launch gap.
// Grid = ceil(n_dst/64) = 782 blocks = 3 blocks/CU at 51KB LDS -> 12
// waves/CU to cover gather latency.
// ---------------------------------------------------------------------------
__global__ __launch_bounds__(256) void fused_agg_gemm_kernel(
    const uint4* __restrict__ Hb, const int* __restrict__ buckets,
    const int* __restrict__ counts, const int* __restrict__ ovcnt,
    const int* __restrict__ ovd, const int* __restrict__ ovs,
    const unsigned short* __restrict__ Wt, const float* __restrict__ b,
    float* __restrict__ out, int n_dst)
{
    __shared__ __align__(16) unsigned char smem[52224];
    unsigned short* Ash = (unsigned short*)smem;                   // [64][LDA]
    unsigned short* Wsh = (unsigned short*)(smem + 64 * LDA * 2);  // [128][LDA]
    float* Csh = (float*)smem;                                     // [64][132]

    const int tid  = threadIdx.x;
    const int lane = tid & 63, wv = tid >> 6;
    const size_t row0 = (size_t)blockIdx.x * 64;
    const int ql = lane & 15, quad = lane >> 4;

    // stage W tile (coalesced 32KB; latency partially overlaps first gathers)
#pragma unroll
    for (int t = 0; t < 8; ++t) {
        int i = tid + t * 256;
        int n = i >> 4, k8 = (i & 15) << 3;
        *(uint4*)&Wsh[n * LDA + k8] = ((const uint4*)Wt)[i];
    }

    int nov = *ovcnt; if (nov > OVCAP) nov = OVCAP;

    // per-wave: degrees for my 16 rows in one lane-spread load
    const int dst0 = (int)row0 + wv * 16;
    int dgv = 0;
    if (lane < 16 && dst0 + lane < n_dst)
        dgv = counts[(size_t)(dst0 + lane) * CSTRIDE];

    // software pipeline: bucket-index load for row r+1 issued before gather r
    int m_cur = __shfl(dgv, 0); m_cur = m_cur < BCAP ? m_cur : BCAP;
    int idx_cur = (lane < m_cur) ? buckets[(size_t)dst0 * BCAP + lane] : 0;

    for (int r = 0; r < 16; ++r) {
        int m_next = 0, idx_next = 0;
        if (r + 1 < 16) {
            m_next = __shfl(dgv, r + 1); m_next = m_next < BCAP ? m_next : BCAP;
            idx_next = (lane < m_next) ? buckets[(size_t)(dst0 + r + 1) * BCAP + lane] : 0;
        }
        int m = m_cur, idx = idx_cur, dst = dst0 + r;

        float acc[8] = {0, 0, 0, 0, 0, 0, 0, 0};
        int j = 0;
        for (; j + 8 <= m; j += 8) {                 // 8 rows in flight
            int sA = __shfl(idx, j + quad);
            int sB = __shfl(idx, j + 4 + quad);
            uint4 ha = Hb[(size_t)sA * 16 + ql];
            uint4 hb = Hb[(size_t)sB * 16 + ql];
            acc[0] += bflo(ha.x) + bflo(hb.x); acc[1] += bfhi(ha.x) + bfhi(hb.x);
            acc[2] += bflo(ha.y) + bflo(hb.y); acc[3] += bfhi(ha.y) + bfhi(hb.y);
            acc[4] += bflo(ha.z) + bflo(hb.z); acc[5] += bfhi(ha.z) + bfhi(hb.z);
            acc[6] += bflo(ha.w) + bflo(hb.w); acc[7] += bfhi(ha.w) + bfhi(hb.w);
        }
        for (; j < m; j += 4) {                      // predicated tail
            int jj = j + quad;
            int s = __shfl(idx, jj < m ? jj : m - 1);
            uint4 hv = Hb[(size_t)s * 16 + ql];
            float w = (jj < m) ? 1.f : 0.f;
            acc[0] += w * bflo(hv.x); acc[1] += w * bfhi(hv.x);
            acc[2] += w * bflo(hv.y); acc[3] += w * bfhi(hv.y);
            acc[4] += w * bflo(hv.z); acc[5] += w * bfhi(hv.z);
            acc[6] += w * bflo(hv.w); acc[7] += w * bfhi(hv.w);
        }
        if (dst < n_dst) {                           // overflow (empty normally)
            for (int k = quad; k < nov; k += 4) {
                if (ovd[k] == dst) {
                    uint4 hv = Hb[(size_t)ovs[k] * 16 + ql];
                    acc[0] += bflo(hv.x); acc[1] += bfhi(hv.x);
                    acc[2] += bflo(hv.y); acc[3] += bfhi(hv.y);
                    acc[4] += bflo(hv.z); acc[5] += bfhi(hv.z);
                    acc[6] += bflo(hv.w); acc[7] += bfhi(hv.w);
                }
            }
        }
#pragma unroll
        for (int k = 0; k < 8; ++k) {
            acc[k] += __shfl_xor(acc[k], 16);
            acc[k] += __shfl_xor(acc[k], 32);
        }
        if (quad == 0) {
            uint4 o;
            o.x = (unsigned)f2bf(acc[0]) | ((unsigned)f2bf(acc[1]) << 16);
            o.y = (unsigned)f2bf(acc[2]) | ((unsigned)f2bf(acc[3]) << 16);
            o.z = (unsigned)f2bf(acc[4]) | ((unsigned)f2bf(acc[5]) << 16);
            o.w = (unsigned)f2bf(acc[6]) | ((unsigned)f2bf(acc[7]) << 16);
            *(uint4*)&Ash[(wv * 16 + r) * LDA + ql * 8] = o;
        }
        m_cur = m_next; idx_cur = idx_next;
    }
    __syncthreads();

    const int m0 = wv * 16;
    const int fl = lane & 15;

    f32x4 cacc[8];
#pragma unroll
    for (int n = 0; n < 8; ++n) cacc[n] = (f32x4){0.f, 0.f, 0.f, 0.f};

#pragma unroll
    for (int kc = 0; kc < 128; kc += 32) {
        bf16x8 a = *(const bf16x8*)&Ash[(m0 + fl) * LDA + kc + quad * 8];
#pragma unroll
        for (int n = 0; n < 8; ++n) {
            bf16x8 bf = *(const bf16x8*)&Wsh[(n * 16 + fl) * LDA + kc + quad * 8];
            cacc[n] = __builtin_amdgcn_mfma_f32_16x16x32_bf16(a, bf, cacc[n], 0, 0, 0);
        }
    }

    float inv[4], gate[4];
#pragma unroll
    for (int r = 0; r < 4; ++r) {
        size_t gr = row0 + m0 + quad * 4 + r;
        int dg = (gr < (size_t)n_dst) ? counts[gr * CSTRIDE] : 0;
        inv[r]  = 1.0f / (float)(dg > 1 ? dg : 1);
        gate[r] = (dg > 0) ? 1.0f : 0.0f;
    }
    __syncthreads();   // Ash/Wsh dead; reuse as Csh

#pragma unroll
    for (int n = 0; n < 8; ++n) {
        int col = n * 16 + fl;
        float bc = b[col];
#pragma unroll
        for (int r = 0; r < 4; ++r) {
            float v = cacc[n][r] * inv[r] + bc * gate[r];
            Csh[(m0 + quad * 4 + r) * 132 + col] = fmaxf(v, 0.0f);
        }
    }
    __syncthreads();

#pragma unroll
    for (int t = 0; t < 8; ++t) {
        int i = tid + t * 256;
        int rr = i >> 5, c4 = i & 31;
        size_t gr = row0 + rr;
        if (gr < (size_t)n_dst) {
            f32x4 vout = *(f32x4*)&Csh[rr * 132 + c4 * 4];
            __builtin_nontemporal_store(vout, (f32x4*)out + gr * (D / 4) + c4);
        }
    }
}

// ---------------------------------------------------------------------------
// Fallback f32 path (workspace too small for Hb): old separate kernels.
// ---------------------------------------------------------------------------
__global__ __launch_bounds__(256) void aggregate_kernel_f32(
    const float* __restrict__ H,
    const int* __restrict__ buckets, const int* __restrict__ counts,
    const int* __restrict__ ovcnt, const int* __restrict__ ovd,
    const int* __restrict__ ovs, unsigned short* __restrict__ aggb, int n_dst)
{
    int dst = blockIdx.x * 4 + (threadIdx.x >> 6);
    if (dst >= n_dst) return;
    int lane = threadIdx.x & 63;
    int dg = counts[(size_t)dst * CSTRIDE];
    int m = dg < BCAP ? dg : BCAP;
    int nov = *ovcnt; if (nov > OVCAP) nov = OVCAP;
    int idx = (lane < m) ? buckets[(size_t)dst * BCAP + lane] : 0;

    const int hl = lane & 31, half = lane >> 5;
    const float4* H4 = (const float4*)H;
    float acc[4] = {0, 0, 0, 0};
    int j = 0;
    for (; j + 4 <= m; j += 4) {
        int sA = __shfl(idx, j + half);
        int sB = __shfl(idx, j + 2 + half);
        float4 va = H4[(size_t)sA * 32 + hl];
        float4 vb = H4[(size_t)sB * 32 + hl];
        acc[0] += va.x + vb.x; acc[1] += va.y + vb.y;
        acc[2] += va.z + vb.z; acc[3] += va.w + vb.w;
    }
    for (; j < m; j += 2) {
        int jj = j + half;
        int s = __shfl(idx, jj < m ? jj : m - 1);
        float4 v = H4[(size_t)s * 32 + hl];
        float w = (jj < m) ? 1.f : 0.f;
        acc[0] += w * v.x; acc[1] += w * v.y;
        acc[2] += w * v.z; acc[3] += w * v.w;
    }
    for (int k = half; k < nov; k += 2) {
        if (ovd[k] == dst) {
            float4 v = H4[(size_t)ovs[k] * 32 + hl];
            acc[0] += v.x; acc[1] += v.y; acc[2] += v.z; acc[3] += v.w;
        }
    }
#pragma unroll
    for (int k = 0; k < 4; ++k) acc[k] += __shfl_xor(acc[k], 32);
    if (half == 0) {
        uint2 o;
        o.x = (unsigned)f2bf(acc[0]) | ((unsigned)f2bf(acc[1]) << 16);
        o.y = (unsigned)f2bf(acc[2]) | ((unsigned)f2bf(acc[3]) << 16);
        ((uint2*)aggb)[(size_t)dst * 32 + hl] = o;
    }
}

__global__ __launch_bounds__(256) void gemm_finalize_kernel(
    const unsigned short* __restrict__ aggb, const unsigned short* __restrict__ Wt,
    const float* __restrict__ b, const int* __restrict__ counts,
    float* __restrict__ out, int n_dst)
{
    __shared__ __align__(16) unsigned char smem[52224];
    unsigned short* Ash = (unsigned short*)smem;                   // [64][LDA]
    unsigned short* Wsh = (unsigned short*)(smem + 64 * LDA * 2);  // [128][LDA]
    float* Csh = (float*)smem;                                     // [64][132]

    const int tid  = threadIdx.x;
    const int lane = tid & 63, wv = tid >> 6;
    const size_t row0 = (size_t)blockIdx.x * 64;

#pragma unroll
    for (int t = 0; t < 4; ++t) {
        int i = tid + t * 256;
        int r = i >> 4, k8 = (i & 15) << 3;
        size_t gr = row0 + r;
        uint4 v = (gr < (size_t)n_dst) ? ((const uint4*)aggb)[gr * 16 + (i & 15)]
                                       : make_uint4(0, 0, 0, 0);
        *(uint4*)&Ash[r * LDA + k8] = v;
    }
#pragma unroll
    for (int t = 0; t < 8; ++t) {
        int i = tid + t * 256;
        int n = i >> 4, k8 = (i & 15) << 3;
        *(uint4*)&Wsh[n * LDA + k8] = ((const uint4*)Wt)[i];
    }
    __syncthreads();

    const int m0 = wv * 16;
    const int fl = lane & 15, quad = lane >> 4;

    f32x4 cacc[8];
#pragma unroll
    for (int n = 0; n < 8; ++n) cacc[n] = (f32x4){0.f, 0.f, 0.f, 0.f};

#pragma unroll
    for (int kc = 0; kc < 128; kc += 32) {
        bf16x8 a = *(const bf16x8*)&Ash[(m0 + fl) * LDA + kc + quad * 8];
#pragma unroll
        for (int n = 0; n < 8; ++n) {
            bf16x8 bf = *(const bf16x8*)&Wsh[(n * 16 + fl) * LDA + kc + quad * 8];
            cacc[n] = __builtin_amdgcn_mfma_f32_16x16x32_bf16(a, bf, cacc[n], 0, 0, 0);
        }
    }

    float inv[4], gate[4];
#pragma unroll
    for (int r = 0; r < 4; ++r) {
        size_t gr = row0 + m0 + quad * 4 + r;
        int dg = (gr < (size_t)n_dst) ? counts[gr * CSTRIDE] : 0;
        inv[r]  = 1.0f / (float)(dg > 1 ? dg : 1);
        gate[r] = (dg > 0) ? 1.0f : 0.0f;
    }
    __syncthreads();   // Ash/Wsh dead; reuse as Csh

#pragma unroll
    for (int n = 0; n < 8; ++n) {
        int col = n * 16 + fl;
        float bc = b[col];
#pragma unroll
        for (int r = 0; r < 4; ++r) {
            float v = cacc[n][r] * inv[r] + bc * gate[r];
            Csh[(m0 + quad * 4 + r) * 132 + col] = fmaxf(v, 0.0f);
        }
    }
    __syncthreads();

#pragma unroll
    for (int t = 0; t < 8; ++t) {
        int i = tid + t * 256;
        int rr = i >> 5, c4 = i & 31;
        size_t gr = row0 + rr;
        if (gr < (size_t)n_dst) {
            f32x4 vout = *(f32x4*)&Csh[rr * 132 + c4 * 4];
            __builtin_nontemporal_store(vout, (f32x4*)out + gr * (D / 4) + c4);
        }
    }
}

extern "C" void kernel_launch(void* const* d_in, const int* in_sizes, int n_in,
                              void* d_out, int out_size, void* d_ws, size_t ws_size,
                              hipStream_t stream) {
    const float* H    = (const float*)d_in[0];   // [N_src, 128]
    const float* W    = (const float*)d_in[1];   // [128, 128]
    const float* b    = (const float*)d_in[2];   // [128]
    const int*   esrc = (const int*)d_in[3];     // [E]
    const int*   edst = (const int*)d_in[4];     // [E]
    const int    E     = in_sizes[3];
    const int    n_dst = out_size / D;
    const int    nsrc_elems = in_sizes[0];       // N_src * 128

    float* out = (float*)d_out;

    // ws: Wt | counts(padded) | ovcnt(pad) | ovd | ovs | buckets | aggb | Hb
    char* p = (char*)d_ws;
    unsigned short* Wt = (unsigned short*)p;  p += 128 * 128 * sizeof(unsigned short);
    int* counts = (int*)p;  p += (size_t)n_dst * CSTRIDE * 4;
    int* ovcnt  = (int*)p;  p += 256;            // zeroed together with counts
    int* ovd    = (int*)p;  p += (size_t)OVCAP * 4;
    int* ovs    = (int*)p;  p += (size_t)OVCAP * 4;
    int* buckets= (int*)p;  p += (size_t)n_dst * BCAP * 4;
    size_t agg_off = (((size_t)(p - (char*)d_ws)) + 255) & ~(size_t)255;
    unsigned short* aggb = (unsigned short*)((char*)d_ws + agg_off);
    size_t hb_off = (agg_off + (size_t)n_dst * D * 2 + 255) & ~(size_t)255;
    bool use_bf16h = (ws_size >= hb_off + (size_t)nsrc_elems * 2);
    unsigned* Hb = (unsigned*)((char*)d_ws + hb_off);

    const int nh8 = use_bf16h ? nsrc_elems / 8 : 0;
    int prep_work = nh8 + 16384;
    if (prep_work < E) prep_work = E;

    // Zero padded counts + overflow cursor in one memset (contiguous, ~3.2MB).
    hipMemsetAsync(counts, 0, (size_t)n_dst * CSTRIDE * 4 + 256, stream);

    if (use_bf16h) {
        prep_kernel<true><<<(prep_work + 255) / 256, 256, 0, stream>>>(
            H, Hb, nh8, W, Wt, esrc, edst, E, counts, buckets, ovcnt, ovd, ovs);
        fused_agg_gemm_kernel<<<(n_dst + 63) / 64, 256, 0, stream>>>(
            (const uint4*)Hb, buckets, counts, ovcnt, ovd, ovs, Wt, b, out, n_dst);
    } else {
        prep_kernel<false><<<(prep_work + 255) / 256, 256, 0, stream>>>(
            H, Hb, nh8, W, Wt, esrc, edst, E, counts, buckets, ovcnt, ovd, ovs);
        aggregate_kernel_f32<<<(n_dst + 3) / 4, 256, 0, stream>>>(
            H, buckets, counts, ovcnt, ovd, ovs, aggb, n_dst);
        gemm_finalize_kernel<<<(n_dst + 63) / 64, 256, 0, stream>>>(
            aggb, Wt, b, counts, out, n_dst);
    }
}

// Round 4
// 171.891 us; speedup vs baseline: 1.1281x; 1.1281x over previous
//
#include <hip/hip_runtime.h>

#define D 128
#define LDA 136     // bf16 elems per LDS row (+8 pad)
#define BCAP 64     // bucket capacity per dst (max degree ~35 for this data)
#define CSTRIDE 16  // counts padded: 1 counter per 64B line
#define OVCAP 65536 // overflow list capacity (correct fallback, empty in practice)

typedef __attribute__((ext_vector_type(8))) short bf16x8;
typedef __attribute__((ext_vector_type(4))) float f32x4;
typedef __attribute__((ext_vector_type(4))) unsigned int u32x4;

static __device__ __forceinline__ unsigned short f2bf(float f) {
    unsigned u = __float_as_uint(f);
    unsigned r = 0x7fffu + ((u >> 16) & 1u);   // round-to-nearest-even
    return (unsigned short)((u + r) >> 16);
}
static __device__ __forceinline__ float bflo(unsigned u) { return __uint_as_float(u << 16); }
static __device__ __forceinline__ float bfhi(unsigned u) { return __uint_as_float(u & 0xffff0000u); }

// ---------------------------------------------------------------------------
// prep_gemm: per block — (1) issue edge loads + count atomics FIRST (their
// latency hides under the GEMM), (2) stage Wsh[n][k]=bf16(W[k][n]) (34KB LDS,
// 4 blocks/CU), (3) one 64-row tile of WH = H@W via MFMA with A-fragments
// loaded DIRECTLY from H f32 global into registers (no A-tile LDS), (4)
// bounce C through LDS (Wsh dead) and store WHb bf16 with PLAIN cached
// stores (round-3 lesson: nt stores on a producer-consumer intermediate
// broke L3 residency, FETCH 71MB), (5) bucket stores (atomic results long
// since landed). Rounding to bf16 now happens at |WH|~1 BEFORE aggregation
// (ulp 2^-9) instead of after the sum at |agg|~3.5 (ulp 2^-7) -> absmax
// should improve.
// ---------------------------------------------------------------------------
__global__ __launch_bounds__(256, 4) void prep_gemm_kernel(
    const float* __restrict__ H, int n_src, const float* __restrict__ W,
    unsigned short* __restrict__ WHb,
    const int* __restrict__ esrc, const int* __restrict__ edst, int E,
    int* __restrict__ counts, int* __restrict__ buckets,
    int* __restrict__ ovcnt, int* __restrict__ ovd, int* __restrict__ ovs)
{
    __shared__ __align__(16) unsigned char smem[34816];
    unsigned short* Wsh = (unsigned short*)smem;   // [128][LDA] bf16, then dead
    float* Csh = (float*)smem;                     // [64][132] f32 (overlay)

    const int tid = threadIdx.x, bid = blockIdx.x;
    const int gt = (int)gridDim.x * 256;

    // --- edges: loads + atomics issued first ---
    int e0 = bid * 256 + tid, e1 = e0 + gt;
    bool h0 = (e0 < E), h1 = (e1 < E);
    int d0 = 0, s0 = 0, d1 = 0, s1 = 0, c0 = 0, c1 = 0;
    if (h0) { d0 = __builtin_nontemporal_load(edst + e0);
              s0 = __builtin_nontemporal_load(esrc + e0); }
    if (h1) { d1 = __builtin_nontemporal_load(edst + e1);
              s1 = __builtin_nontemporal_load(esrc + e1); }
    if (h0) c0 = atomicAdd(&counts[(size_t)d0 * CSTRIDE], 1);
    if (h1) c1 = atomicAdd(&counts[(size_t)d1 * CSTRIDE], 1);

    // --- stage Wsh[n][k] = bf16(W[k][n]) (W is L2-hot across blocks) ---
    const f32x4* W4 = (const f32x4*)W;
#pragma unroll
    for (int t = 0; t < 16; ++t) {
        int i4 = tid + t * 256;
        f32x4 w = W4[i4];
        int ib = i4 * 4;
        Wsh[((ib + 0) & 127) * LDA + ((ib + 0) >> 7)] = f2bf(w.x);
        Wsh[((ib + 1) & 127) * LDA + ((ib + 1) >> 7)] = f2bf(w.y);
        Wsh[((ib + 2) & 127) * LDA + ((ib + 2) >> 7)] = f2bf(w.z);
        Wsh[((ib + 3) & 127) * LDA + ((ib + 3) >> 7)] = f2bf(w.w);
    }
    __syncthreads();

    const int lane = tid & 63, wvid = tid >> 6;
    const int fl = lane & 15, quad = lane >> 4;
    const int rowbase = bid * 64;
    const bool doG = (rowbase < n_src);

    f32x4 cacc[8];
#pragma unroll
    for (int n = 0; n < 8; ++n) cacc[n] = (f32x4){0.f, 0.f, 0.f, 0.f};

    if (doG) {
        // A-fragments straight from H: row = rowbase + wvid*16 + fl,
        // cols kc + quad*8 .. +8 for kc in {0,32,64,96}
        int arow = rowbase + wvid * 16 + fl;
        bool rok = (arow < n_src);
        const f32x4* H4 = (const f32x4*)H;
        size_t base = (size_t)arow * 32 + quad * 2;
        f32x4 z = (f32x4){0.f, 0.f, 0.f, 0.f};
        f32x4 av0 = rok ? H4[base +  0] : z, av1 = rok ? H4[base +  1] : z;
        f32x4 av2 = rok ? H4[base +  8] : z, av3 = rok ? H4[base +  9] : z;
        f32x4 av4 = rok ? H4[base + 16] : z, av5 = rok ? H4[base + 17] : z;
        f32x4 av6 = rok ? H4[base + 24] : z, av7 = rok ? H4[base + 25] : z;

#define PACK_A(a, v0, v1)                                                    \
        { a[0] = (short)f2bf(v0.x); a[1] = (short)f2bf(v0.y);                \
          a[2] = (short)f2bf(v0.z); a[3] = (short)f2bf(v0.w);                \
          a[4] = (short)f2bf(v1.x); a[5] = (short)f2bf(v1.y);                \
          a[6] = (short)f2bf(v1.z); a[7] = (short)f2bf(v1.w); }
#define MSTEP(a, KC)                                                          \
        _Pragma("unroll")                                                     \
        for (int n = 0; n < 8; ++n) {                                         \
            bf16x8 bf = *(const bf16x8*)&Wsh[(n * 16 + fl) * LDA + (KC) + quad * 8]; \
            cacc[n] = __builtin_amdgcn_mfma_f32_16x16x32_bf16(a, bf, cacc[n], 0, 0, 0); \
        }
        bf16x8 a0, a1, a2, a3;
        PACK_A(a0, av0, av1) PACK_A(a1, av2, av3)
        PACK_A(a2, av4, av5) PACK_A(a3, av6, av7)
        MSTEP(a0, 0) MSTEP(a1, 32) MSTEP(a2, 64) MSTEP(a3, 96)
#undef PACK_A
#undef MSTEP
    }
    __syncthreads();   // Wsh dead; overlay Csh

    if (doG) {
#pragma unroll
        for (int n = 0; n < 8; ++n) {
            int col = n * 16 + fl;
#pragma unroll
            for (int r = 0; r < 4; ++r)
                Csh[(wvid * 16 + quad * 4 + r) * 132 + col] = cacc[n][r];
        }
    }
    __syncthreads();

    if (doG) {
#pragma unroll
        for (int t = 0; t < 4; ++t) {
            int i = tid + t * 256;
            int rr = i >> 4, cu = i & 15;
            size_t gr = (size_t)rowbase + rr;
            if (gr < (size_t)n_src) {
                float* s = &Csh[rr * 132 + cu * 8];
                f32x4 lo = *(f32x4*)s, hi = *(f32x4*)(s + 4);
                u32x4 o;
                o.x = (unsigned)f2bf(lo.x) | ((unsigned)f2bf(lo.y) << 16);
                o.y = (unsigned)f2bf(lo.z) | ((unsigned)f2bf(lo.w) << 16);
                o.z = (unsigned)f2bf(hi.x) | ((unsigned)f2bf(hi.y) << 16);
                o.w = (unsigned)f2bf(hi.z) | ((unsigned)f2bf(hi.w) << 16);
                ((u32x4*)WHb)[gr * 16 + cu] = o;   // PLAIN store: keep L3-resident
            }
        }
    }

    // --- bucket stores (atomic results landed long ago) ---
    if (h0) {
        if (c0 < BCAP) buckets[(size_t)d0 * BCAP + c0] = s0;
        else { int o = atomicAdd(ovcnt, 1); if (o < OVCAP) { ovd[o] = d0; ovs[o] = s0; } }
    }
    if (h1) {
        if (c1 < BCAP) buckets[(size_t)d1 * BCAP + c1] = s1;
        else { int o = atomicAdd(ovcnt, 1); if (o < OVCAP) { ovd[o] = d1; ovs[o] = s1; } }
    }
    // cold remainder (only if E > 2*grid threads; empty here)
    for (int e = e0 + 2 * gt; e < E; e += gt) {
        int dd = edst[e], ss = esrc[e];
        int cc = atomicAdd(&counts[(size_t)dd * CSTRIDE], 1);
        if (cc < BCAP) buckets[(size_t)dd * BCAP + cc] = ss;
        else { int o = atomicAdd(ovcnt, 1); if (o < OVCAP) { ovd[o] = dd; ovs[o] = ss; } }
    }
}

// ---------------------------------------------------------------------------
// agg_finalize: one wave per dst row; gather WHb rows (verified loop), then
// out = relu(sum/max(deg,1) + (deg>0 ? b : 0)) written directly (nt, write-
// once). No LDS -> full occupancy for the latency-bound gather (round-3
// lesson: LDS-starved gather = 17% occupancy = slow).
// ---------------------------------------------------------------------------
__global__ __launch_bounds__(256) void agg_finalize_kernel(
    const uint4* __restrict__ WHb, const int* __restrict__ buckets,
    const int* __restrict__ counts, const int* __restrict__ ovcnt,
    const int* __restrict__ ovd, const int* __restrict__ ovs,
    const float* __restrict__ b, float* __restrict__ out, int n_dst)
{
    int dst = blockIdx.x * 4 + (threadIdx.x >> 6);
    if (dst >= n_dst) return;
    int lane = threadIdx.x & 63;
    int dg = counts[(size_t)dst * CSTRIDE];
    int m = dg < BCAP ? dg : BCAP;
    int nov = *ovcnt; if (nov > OVCAP) nov = OVCAP;
    int idx = (lane < m) ? buckets[(size_t)dst * BCAP + lane] : 0;

    const int ql = lane & 15, quad = lane >> 4;
    float acc[8] = {0, 0, 0, 0, 0, 0, 0, 0};
    int j = 0;
    for (; j + 8 <= m; j += 8) {                 // 8 rows in flight
        int sA = __shfl(idx, j + quad);
        int sB = __shfl(idx, j + 4 + quad);
        uint4 ha = WHb[(size_t)sA * 16 + ql];
        uint4 hb = WHb[(size_t)sB * 16 + ql];
        acc[0] += bflo(ha.x) + bflo(hb.x); acc[1] += bfhi(ha.x) + bfhi(hb.x);
        acc[2] += bflo(ha.y) + bflo(hb.y); acc[3] += bfhi(ha.y) + bfhi(hb.y);
        acc[4] += bflo(ha.z) + bflo(hb.z); acc[5] += bfhi(ha.z) + bfhi(hb.z);
        acc[6] += bflo(ha.w) + bflo(hb.w); acc[7] += bfhi(ha.w) + bfhi(hb.w);
    }
    for (; j < m; j += 4) {                      // predicated tail
        int jj = j + quad;
        int s = __shfl(idx, jj < m ? jj : m - 1);
        uint4 hv = WHb[(size_t)s * 16 + ql];
        float w = (jj < m) ? 1.f : 0.f;
        acc[0] += w * bflo(hv.x); acc[1] += w * bfhi(hv.x);
        acc[2] += w * bflo(hv.y); acc[3] += w * bfhi(hv.y);
        acc[4] += w * bflo(hv.z); acc[5] += w * bfhi(hv.z);
        acc[6] += w * bflo(hv.w); acc[7] += w * bfhi(hv.w);
    }
    for (int k = quad; k < nov; k += 4) {        // overflow (empty normally)
        if (ovd[k] == dst) {
            uint4 hv = WHb[(size_t)ovs[k] * 16 + ql];
            acc[0] += bflo(hv.x); acc[1] += bfhi(hv.x);
            acc[2] += bflo(hv.y); acc[3] += bfhi(hv.y);
            acc[4] += bflo(hv.z); acc[5] += bfhi(hv.z);
            acc[6] += bflo(hv.w); acc[7] += bfhi(hv.w);
        }
    }
#pragma unroll
    for (int k = 0; k < 8; ++k) {
        acc[k] += __shfl_xor(acc[k], 16);
        acc[k] += __shfl_xor(acc[k], 32);
    }
    if (quad == 0) {
        float inv  = 1.0f / (float)(dg > 1 ? dg : 1);
        float gate = (dg > 0) ? 1.0f : 0.0f;
        const f32x4* b4 = (const f32x4*)b;
        f32x4 b0 = b4[ql * 2], b1 = b4[ql * 2 + 1];
        f32x4 o0, o1;
        o0.x = fmaxf(acc[0] * inv + b0.x * gate, 0.f);
        o0.y = fmaxf(acc[1] * inv + b0.y * gate, 0.f);
        o0.z = fmaxf(acc[2] * inv + b0.z * gate, 0.f);
        o0.w = fmaxf(acc[3] * inv + b0.w * gate, 0.f);
        o1.x = fmaxf(acc[4] * inv + b1.x * gate, 0.f);
        o1.y = fmaxf(acc[5] * inv + b1.y * gate, 0.f);
        o1.z = fmaxf(acc[6] * inv + b1.z * gate, 0.f);
        o1.w = fmaxf(acc[7] * inv + b1.w * gate, 0.f);
        f32x4* op = (f32x4*)out + (size_t)dst * 32 + ql * 2;
        __builtin_nontemporal_store(o0, op);
        __builtin_nontemporal_store(o1, op + 1);
    }
}

// ---------------------------------------------------------------------------
// Fallback path (workspace too small for WHb): edges+Wt prep, f32 gather,
// MFMA gemm_finalize. Functionally verified in earlier rounds.
// ---------------------------------------------------------------------------
__global__ __launch_bounds__(256) void prep_fb_kernel(
    const float* __restrict__ W, unsigned short* __restrict__ Wt,
    const int* __restrict__ esrc, const int* __restrict__ edst, int E,
    int* __restrict__ counts, int* __restrict__ buckets,
    int* __restrict__ ovcnt, int* __restrict__ ovd, int* __restrict__ ovs)
{
    int i = blockIdx.x * 256 + threadIdx.x;
    int d = 0, s = 0, c = 0;
    bool hasE = (i < E);
    if (hasE) { d = edst[i]; s = esrc[i]; }
    if (hasE) c = atomicAdd(&counts[(size_t)d * CSTRIDE], 1);
    if (i < 16384) {                       // Wt[n][k] = bf16(W[k][n])
        int k = i >> 7, n = i & 127;
        Wt[n * 128 + k] = f2bf(W[i]);
    }
    if (hasE) {
        if (c < BCAP) buckets[(size_t)d * BCAP + c] = s;
        else { int o = atomicAdd(ovcnt, 1); if (o < OVCAP) { ovd[o] = d; ovs[o] = s; } }
    }
}

__global__ __launch_bounds__(256) void aggregate_kernel_f32(
    const float* __restrict__ H,
    const int* __restrict__ buckets, const int* __restrict__ counts,
    const int* __restrict__ ovcnt, const int* __restrict__ ovd,
    const int* __restrict__ ovs, unsigned short* __restrict__ aggb, int n_dst)
{
    int dst = blockIdx.x * 4 + (threadIdx.x >> 6);
    if (dst >= n_dst) return;
    int lane = threadIdx.x & 63;
    int dg = counts[(size_t)dst * CSTRIDE];
    int m = dg < BCAP ? dg : BCAP;
    int nov = *ovcnt; if (nov > OVCAP) nov = OVCAP;
    int idx = (lane < m) ? buckets[(size_t)dst * BCAP + lane] : 0;

    const int hl = lane & 31, half = lane >> 5;
    const float4* H4 = (const float4*)H;
    float acc[4] = {0, 0, 0, 0};
    int j = 0;
    for (; j + 4 <= m; j += 4) {
        int sA = __shfl(idx, j + half);
        int sB = __shfl(idx, j + 2 + half);
        float4 va = H4[(size_t)sA * 32 + hl];
        float4 vb = H4[(size_t)sB * 32 + hl];
        acc[0] += va.x + vb.x; acc[1] += va.y + vb.y;
        acc[2] += va.z + vb.z; acc[3] += va.w + vb.w;
    }
    for (; j < m; j += 2) {
        int jj = j + half;
        int s = __shfl(idx, jj < m ? jj : m - 1);
        float4 v = H4[(size_t)s * 32 + hl];
        float w = (jj < m) ? 1.f : 0.f;
        acc[0] += w * v.x; acc[1] += w * v.y;
        acc[2] += w * v.z; acc[3] += w * v.w;
    }
    for (int k = half; k < nov; k += 2) {
        if (ovd[k] == dst) {
            float4 v = H4[(size_t)ovs[k] * 32 + hl];
            acc[0] += v.x; acc[1] += v.y; acc[2] += v.z; acc[3] += v.w;
        }
    }
#pragma unroll
    for (int k = 0; k < 4; ++k) acc[k] += __shfl_xor(acc[k], 32);
    if (half == 0) {
        uint2 o;
        o.x = (unsigned)f2bf(acc[0]) | ((unsigned)f2bf(acc[1]) << 16);
        o.y = (unsigned)f2bf(acc[2]) | ((unsigned)f2bf(acc[3]) << 16);
        ((uint2*)aggb)[(size_t)dst * 32 + hl] = o;
    }
}

__global__ __launch_bounds__(256) void gemm_finalize_kernel(
    const unsigned short* __restrict__ aggb, const unsigned short* __restrict__ Wt,
    const float* __restrict__ b, const int* __restrict__ counts,
    float* __restrict__ out, int n_dst)
{
    __shared__ __align__(16) unsigned char smem[52224];
    unsigned short* Ash = (unsigned short*)smem;                   // [64][LDA]
    unsigned short* Wsh = (unsigned short*)(smem + 64 * LDA * 2);  // [128][LDA]
    float* Csh = (float*)smem;                                     // [64][132]

    const int tid  = threadIdx.x;
    const int lane = tid & 63, wv = tid >> 6;
    const size_t row0 = (size_t)blockIdx.x * 64;

#pragma unroll
    for (int t = 0; t < 4; ++t) {
        int i = tid + t * 256;
        int r = i >> 4, k8 = (i & 15) << 3;
        size_t gr = row0 + r;
        uint4 v = (gr < (size_t)n_dst) ? ((const uint4*)aggb)[gr * 16 + (i & 15)]
                                       : make_uint4(0, 0, 0, 0);
        *(uint4*)&Ash[r * LDA + k8] = v;
    }
#pragma unroll
    for (int t = 0; t < 8; ++t) {
        int i = tid + t * 256;
        int n = i >> 4, k8 = (i & 15) << 3;
        *(uint4*)&Wsh[n * LDA + k8] = ((const uint4*)Wt)[i];
    }
    __syncthreads();

    const int m0 = wv * 16;
    const int fl = lane & 15, quad = lane >> 4;

    f32x4 cacc[8];
#pragma unroll
    for (int n = 0; n < 8; ++n) cacc[n] = (f32x4){0.f, 0.f, 0.f, 0.f};

#pragma unroll
    for (int kc = 0; kc < 128; kc += 32) {
        bf16x8 a = *(const bf16x8*)&Ash[(m0 + fl) * LDA + kc + quad * 8];
#pragma unroll
        for (int n = 0; n < 8; ++n) {
            bf16x8 bf = *(const bf16x8*)&Wsh[(n * 16 + fl) * LDA + kc + quad * 8];
            cacc[n] = __builtin_amdgcn_mfma_f32_16x16x32_bf16(a, bf, cacc[n], 0, 0, 0);
        }
    }

    float inv[4], gate[4];
#pragma unroll
    for (int r = 0; r < 4; ++r) {
        size_t gr = row0 + m0 + quad * 4 + r;
        int dg = (gr < (size_t)n_dst) ? counts[gr * CSTRIDE] : 0;
        inv[r]  = 1.0f / (float)(dg > 1 ? dg : 1);
        gate[r] = (dg > 0) ? 1.0f : 0.0f;
    }
    __syncthreads();   // Ash/Wsh dead; reuse as Csh

#pragma unroll
    for (int n = 0; n < 8; ++n) {
        int col = n * 16 + fl;
        float bc = b[col];
#pragma unroll
        for (int r = 0; r < 4; ++r) {
            float v = cacc[n][r] * inv[r] + bc * gate[r];
            Csh[(m0 + quad * 4 + r) * 132 + col] = fmaxf(v, 0.0f);
        }
    }
    __syncthreads();

#pragma unroll
    for (int t = 0; t < 8; ++t) {
        int i = tid + t * 256;
        int rr = i >> 5, c4 = i & 31;
        size_t gr = row0 + rr;
        if (gr < (size_t)n_dst) {
            f32x4 vout = *(f32x4*)&Csh[rr * 132 + c4 * 4];
            __builtin_nontemporal_store(vout, (f32x4*)out + gr * (D / 4) + c4);
        }
    }
}

extern "C" void kernel_launch(void* const* d_in, const int* in_sizes, int n_in,
                              void* d_out, int out_size, void* d_ws, size_t ws_size,
                              hipStream_t stream) {
    const float* H    = (const float*)d_in[0];   // [N_src, 128]
    const float* W    = (const float*)d_in[1];   // [128, 128]
    const float* b    = (const float*)d_in[2];   // [128]
    const int*   esrc = (const int*)d_in[3];     // [E]
    const int*   edst = (const int*)d_in[4];     // [E]
    const int    E     = in_sizes[3];
    const int    n_dst = out_size / D;
    const int    nsrc_elems = in_sizes[0];       // N_src * 128
    const int    n_src = nsrc_elems / D;

    float* out = (float*)d_out;

    // ws: Wt | counts(padded) | ovcnt(pad) | ovd | ovs | buckets | aggb | WHb
    char* p = (char*)d_ws;
    unsigned short* Wt = (unsigned short*)p;  p += 128 * 128 * sizeof(unsigned short);
    int* counts = (int*)p;  p += (size_t)n_dst * CSTRIDE * 4;
    int* ovcnt  = (int*)p;  p += 256;            // zeroed together with counts
    int* ovd    = (int*)p;  p += (size_t)OVCAP * 4;
    int* ovs    = (int*)p;  p += (size_t)OVCAP * 4;
    int* buckets= (int*)p;  p += (size_t)n_dst * BCAP * 4;
    size_t agg_off = (((size_t)(p - (char*)d_ws)) + 255) & ~(size_t)255;
    unsigned short* aggb = (unsigned short*)((char*)d_ws + agg_off);
    size_t wh_off = (agg_off + (size_t)n_dst * D * 2 + 255) & ~(size_t)255;
    bool use_wh = (ws_size >= wh_off + (size_t)nsrc_elems * 2);
    unsigned short* WHb = (unsigned short*)((char*)d_ws + wh_off);

    // Zero padded counts + overflow cursor in one memset (contiguous, ~3.2MB).
    hipMemsetAsync(counts, 0, (size_t)n_dst * CSTRIDE * 4 + 256, stream);

    if (use_wh) {
        int G = (n_src + 63) / 64;
        int Ge = (E + 511) / 512;
        if (Ge > G) G = Ge;
        prep_gemm_kernel<<<G, 256, 0, stream>>>(
            H, n_src, W, WHb, esrc, edst, E, counts, buckets, ovcnt, ovd, ovs);
        agg_finalize_kernel<<<(n_dst + 3) / 4, 256, 0, stream>>>(
            (const uint4*)WHb, buckets, counts, ovcnt, ovd, ovs, b, out, n_dst);
    } else {
        int prep_work = E > 16384 ? E : 16384;
        prep_fb_kernel<<<(prep_work + 255) / 256, 256, 0, stream>>>(
            W, Wt, esrc, edst, E, counts, buckets, ovcnt, ovd, ovs);
        aggregate_kernel_f32<<<(n_dst + 3) / 4, 256, 0, stream>>>(
            H, buckets, counts, ovcnt, ovd, ovs, aggb, n_dst);
        gemm_finalize_kernel<<<(n_dst + 63) / 64, 256, 0, stream>>>(
            aggb, Wt, b, counts, out, n_dst);
    }
}

// Round 5
// 163.094 us; speedup vs baseline: 1.1889x; 1.0539x over previous
//
#include <hip/hip_runtime.h>

#define D 128
#define LDA 136     // bf16 elems per LDS row (+8 pad)
#define BCAP 64     // bucket capacity per dst (max degree ~35 for this data)
#define CSTRIDE 16  // counts padded: 1 counter per 64B line
#define OVCAP 65536 // overflow list capacity (correct fallback, empty in practice)

typedef __attribute__((ext_vector_type(8))) short bf16x8;
typedef __attribute__((ext_vector_type(4))) float f32x4;
typedef __attribute__((ext_vector_type(4))) unsigned int u32x4;

static __device__ __forceinline__ unsigned short f2bf(float f) {
    unsigned u = __float_as_uint(f);
    unsigned r = 0x7fffu + ((u >> 16) & 1u);   // round-to-nearest-even
    return (unsigned short)((u + r) >> 16);
}
static __device__ __forceinline__ float bflo(unsigned u) { return __uint_as_float(u << 16); }
static __device__ __forceinline__ float bfhi(unsigned u) { return __uint_as_float(u & 0xffff0000u); }

// ---------------------------------------------------------------------------
// zero_wt: replaces hipMemsetAsync (same dispatch count). Zeros counts +
// ovcnt with vector stores AND writes Wt[n][k] = bf16(W[k][n]) with
// COALESCED dword stores (reads are uncoalesced but W is 64KB, cache-hot).
// This moves the W transpose out of prep_gemm, whose in-LDS transpose was
// a 32-way bank conflict costing ~20us (round-4 counter: 1.28e7 conflicts).
// ---------------------------------------------------------------------------
__global__ __launch_bounds__(256) void zero_wt_kernel(
    const float* __restrict__ W, unsigned short* __restrict__ Wt,
    int* __restrict__ counts, int nz4)
{
    int i = blockIdx.x * 256 + threadIdx.x;
    if (i < nz4) ((u32x4*)counts)[i] = (u32x4){0u, 0u, 0u, 0u};
    if (i < 8192) {                          // 2 consecutive k per thread
        int n = i >> 6, k2 = (i & 63) << 1;
        unsigned lo = f2bf(W[(size_t)k2 * 128 + n]);
        unsigned hi = f2bf(W[(size_t)(k2 + 1) * 128 + n]);
        ((unsigned*)Wt)[(size_t)n * 64 + (k2 >> 1)] = lo | (hi << 16);
    }
}

// ---------------------------------------------------------------------------
// prep_gemm: per block — (1) edge loads + count atomics FIRST (latency hides
// under the GEMM), (2) stage Wsh[n][k] from PRE-TRANSPOSED Wt with b128
// writes (conflict-free; round-4 lesson: in-LDS transpose = 32-way conflict),
// (3) one 64-row tile of WH = H@W via MFMA, A-fragments straight from H f32
// global (no A LDS), (4) Csh bounce (Wsh dead) -> WHb bf16 PLAIN stores
// (round-3 lesson: nt stores on producer-consumer intermediates break L3
// residency), (5) bucket stores (atomic results long landed).
// ---------------------------------------------------------------------------
__global__ __launch_bounds__(256, 4) void prep_gemm_kernel(
    const float* __restrict__ H, int n_src,
    const unsigned short* __restrict__ Wt, unsigned short* __restrict__ WHb,
    const int* __restrict__ esrc, const int* __restrict__ edst, int E,
    int* __restrict__ counts, int* __restrict__ buckets,
    int* __restrict__ ovcnt, int* __restrict__ ovd, int* __restrict__ ovs)
{
    __shared__ __align__(16) unsigned char smem[34816];
    unsigned short* Wsh = (unsigned short*)smem;   // [128][LDA] bf16, then dead
    float* Csh = (float*)smem;                     // [64][132] f32 (overlay)

    const int tid = threadIdx.x, bid = blockIdx.x;
    const int gt = (int)gridDim.x * 256;

    // --- edges: loads + atomics issued first ---
    int e0 = bid * 256 + tid, e1 = e0 + gt;
    bool h0 = (e0 < E), h1 = (e1 < E);
    int d0 = 0, s0 = 0, d1 = 0, s1 = 0, c0 = 0, c1 = 0;
    if (h0) { d0 = __builtin_nontemporal_load(edst + e0);
              s0 = __builtin_nontemporal_load(esrc + e0); }
    if (h1) { d1 = __builtin_nontemporal_load(edst + e1);
              s1 = __builtin_nontemporal_load(esrc + e1); }
    if (h0) c0 = atomicAdd(&counts[(size_t)d0 * CSTRIDE], 1);
    if (h1) c1 = atomicAdd(&counts[(size_t)d1 * CSTRIDE], 1);

    // --- stage Wsh[n][k] from Wt: b128, conflict-free (verified pattern) ---
#pragma unroll
    for (int t = 0; t < 8; ++t) {
        int i = tid + t * 256;
        int n = i >> 4, k8 = (i & 15) << 3;
        *(uint4*)&Wsh[n * LDA + k8] = ((const uint4*)Wt)[i];
    }
    __syncthreads();

    const int lane = tid & 63, wvid = tid >> 6;
    const int fl = lane & 15, quad = lane >> 4;
    const int rowbase = bid * 64;
    const bool doG = (rowbase < n_src);

    f32x4 cacc[8];
#pragma unroll
    for (int n = 0; n < 8; ++n) cacc[n] = (f32x4){0.f, 0.f, 0.f, 0.f};

    if (doG) {
        // A-fragments straight from H: row = rowbase + wvid*16 + fl,
        // cols kc + quad*8 .. +8 for kc in {0,32,64,96}
        int arow = rowbase + wvid * 16 + fl;
        bool rok = (arow < n_src);
        const f32x4* H4 = (const f32x4*)H;
        size_t base = (size_t)arow * 32 + quad * 2;
        f32x4 z = (f32x4){0.f, 0.f, 0.f, 0.f};
        f32x4 av0 = rok ? H4[base +  0] : z, av1 = rok ? H4[base +  1] : z;
        f32x4 av2 = rok ? H4[base +  8] : z, av3 = rok ? H4[base +  9] : z;
        f32x4 av4 = rok ? H4[base + 16] : z, av5 = rok ? H4[base + 17] : z;
        f32x4 av6 = rok ? H4[base + 24] : z, av7 = rok ? H4[base + 25] : z;

#define PACK_A(a, v0, v1)                                                    \
        { a[0] = (short)f2bf(v0.x); a[1] = (short)f2bf(v0.y);                \
          a[2] = (short)f2bf(v0.z); a[3] = (short)f2bf(v0.w);                \
          a[4] = (short)f2bf(v1.x); a[5] = (short)f2bf(v1.y);                \
          a[6] = (short)f2bf(v1.z); a[7] = (short)f2bf(v1.w); }
#define MSTEP(a, KC)                                                          \
        _Pragma("unroll")                                                     \
        for (int n = 0; n < 8; ++n) {                                         \
            bf16x8 bf = *(const bf16x8*)&Wsh[(n * 16 + fl) * LDA + (KC) + quad * 8]; \
            cacc[n] = __builtin_amdgcn_mfma_f32_16x16x32_bf16(a, bf, cacc[n], 0, 0, 0); \
        }
        bf16x8 a0, a1, a2, a3;
        PACK_A(a0, av0, av1) PACK_A(a1, av2, av3)
        PACK_A(a2, av4, av5) PACK_A(a3, av6, av7)
        MSTEP(a0, 0) MSTEP(a1, 32) MSTEP(a2, 64) MSTEP(a3, 96)
#undef PACK_A
#undef MSTEP
    }
    __syncthreads();   // Wsh dead; overlay Csh

    if (doG) {
#pragma unroll
        for (int n = 0; n < 8; ++n) {
            int col = n * 16 + fl;
#pragma unroll
            for (int r = 0; r < 4; ++r)
                Csh[(wvid * 16 + quad * 4 + r) * 132 + col] = cacc[n][r];
        }
    }
    __syncthreads();

    if (doG) {
#pragma unroll
        for (int t = 0; t < 4; ++t) {
            int i = tid + t * 256;
            int rr = i >> 4, cu = i & 15;
            size_t gr = (size_t)rowbase + rr;
            if (gr < (size_t)n_src) {
                float* s = &Csh[rr * 132 + cu * 8];
                f32x4 lo = *(f32x4*)s, hi = *(f32x4*)(s + 4);
                u32x4 o;
                o.x = (unsigned)f2bf(lo.x) | ((unsigned)f2bf(lo.y) << 16);
                o.y = (unsigned)f2bf(lo.z) | ((unsigned)f2bf(lo.w) << 16);
                o.z = (unsigned)f2bf(hi.x) | ((unsigned)f2bf(hi.y) << 16);
                o.w = (unsigned)f2bf(hi.z) | ((unsigned)f2bf(hi.w) << 16);
                ((u32x4*)WHb)[gr * 16 + cu] = o;   // PLAIN store: keep L3-resident
            }
        }
    }

    // --- bucket stores (atomic results landed long ago) ---
    if (h0) {
        if (c0 < BCAP) buckets[(size_t)d0 * BCAP + c0] = s0;
        else { int o = atomicAdd(ovcnt, 1); if (o < OVCAP) { ovd[o] = d0; ovs[o] = s0; } }
    }
    if (h1) {
        if (c1 < BCAP) buckets[(size_t)d1 * BCAP + c1] = s1;
        else { int o = atomicAdd(ovcnt, 1); if (o < OVCAP) { ovd[o] = d1; ovs[o] = s1; } }
    }
    // cold remainder (only if E > 2*grid threads; empty here)
    for (int e = e0 + 2 * gt; e < E; e += gt) {
        int dd = edst[e], ss = esrc[e];
        int cc = atomicAdd(&counts[(size_t)dd * CSTRIDE], 1);
        if (cc < BCAP) buckets[(size_t)dd * BCAP + cc] = ss;
        else { int o = atomicAdd(ovcnt, 1); if (o < OVCAP) { ovd[o] = dd; ovs[o] = ss; } }
    }
}

// ---------------------------------------------------------------------------
// agg_finalize: one wave per dst row; gather WHb rows (verified loop), then
// out = relu(sum/max(deg,1) + (deg>0 ? b : 0)) written directly (nt, write-
// once). No LDS -> full occupancy for the latency-bound gather (round-3
// lesson: LDS-starved gather = 17% occupancy = slow).
// ---------------------------------------------------------------------------
__global__ __launch_bounds__(256) void agg_finalize_kernel(
    const uint4* __restrict__ WHb, const int* __restrict__ buckets,
    const int* __restrict__ counts, const int* __restrict__ ovcnt,
    const int* __restrict__ ovd, const int* __restrict__ ovs,
    const float* __restrict__ b, float* __restrict__ out, int n_dst)
{
    int dst = blockIdx.x * 4 + (threadIdx.x >> 6);
    if (dst >= n_dst) return;
    int lane = threadIdx.x & 63;
    int dg = counts[(size_t)dst * CSTRIDE];
    int m = dg < BCAP ? dg : BCAP;
    int nov = *ovcnt; if (nov > OVCAP) nov = OVCAP;
    int idx = (lane < m) ? buckets[(size_t)dst * BCAP + lane] : 0;

    const int ql = lane & 15, quad = lane >> 4;
    float acc[8] = {0, 0, 0, 0, 0, 0, 0, 0};
    int j = 0;
    for (; j + 8 <= m; j += 8) {                 // 8 rows in flight
        int sA = __shfl(idx, j + quad);
        int sB = __shfl(idx, j + 4 + quad);
        uint4 ha = WHb[(size_t)sA * 16 + ql];
        uint4 hb = WHb[(size_t)sB * 16 + ql];
        acc[0] += bflo(ha.x) + bflo(hb.x); acc[1] += bfhi(ha.x) + bfhi(hb.x);
        acc[2] += bflo(ha.y) + bflo(hb.y); acc[3] += bfhi(ha.y) + bfhi(hb.y);
        acc[4] += bflo(ha.z) + bflo(hb.z); acc[5] += bfhi(ha.z) + bfhi(hb.z);
        acc[6] += bflo(ha.w) + bflo(hb.w); acc[7] += bfhi(ha.w) + bfhi(hb.w);
    }
    for (; j < m; j += 4) {                      // predicated tail
        int jj = j + quad;
        int s = __shfl(idx, jj < m ? jj : m - 1);
        uint4 hv = WHb[(size_t)s * 16 + ql];
        float w = (jj < m) ? 1.f : 0.f;
        acc[0] += w * bflo(hv.x); acc[1] += w * bfhi(hv.x);
        acc[2] += w * bflo(hv.y); acc[3] += w * bfhi(hv.y);
        acc[4] += w * bflo(hv.z); acc[5] += w * bfhi(hv.z);
        acc[6] += w * bflo(hv.w); acc[7] += w * bfhi(hv.w);
    }
    for (int k = quad; k < nov; k += 4) {        // overflow (empty normally)
        if (ovd[k] == dst) {
            uint4 hv = WHb[(size_t)ovs[k] * 16 + ql];
            acc[0] += bflo(hv.x); acc[1] += bfhi(hv.x);
            acc[2] += bflo(hv.y); acc[3] += bfhi(hv.y);
            acc[4] += bflo(hv.z); acc[5] += bfhi(hv.z);
            acc[6] += bflo(hv.w); acc[7] += bfhi(hv.w);
        }
    }
#pragma unroll
    for (int k = 0; k < 8; ++k) {
        acc[k] += __shfl_xor(acc[k], 16);
        acc[k] += __shfl_xor(acc[k], 32);
    }
    if (quad == 0) {
        float inv  = 1.0f / (float)(dg > 1 ? dg : 1);
        float gate = (dg > 0) ? 1.0f : 0.0f;
        const f32x4* b4 = (const f32x4*)b;
        f32x4 b0 = b4[ql * 2], b1 = b4[ql * 2 + 1];
        f32x4 o0, o1;
        o0.x = fmaxf(acc[0] * inv + b0.x * gate, 0.f);
        o0.y = fmaxf(acc[1] * inv + b0.y * gate, 0.f);
        o0.z = fmaxf(acc[2] * inv + b0.z * gate, 0.f);
        o0.w = fmaxf(acc[3] * inv + b0.w * gate, 0.f);
        o1.x = fmaxf(acc[4] * inv + b1.x * gate, 0.f);
        o1.y = fmaxf(acc[5] * inv + b1.y * gate, 0.f);
        o1.z = fmaxf(acc[6] * inv + b1.z * gate, 0.f);
        o1.w = fmaxf(acc[7] * inv + b1.w * gate, 0.f);
        f32x4* op = (f32x4*)out + (size_t)dst * 32 + ql * 2;
        __builtin_nontemporal_store(o0, op);
        __builtin_nontemporal_store(o1, op + 1);
    }
}

// ---------------------------------------------------------------------------
// Fallback path (workspace too small for WHb): edges-only prep, f32 gather,
// MFMA gemm_finalize (Wt comes from zero_wt). Verified in earlier rounds.
// ---------------------------------------------------------------------------
__global__ __launch_bounds__(256) void prep_fb_kernel(
    const int* __restrict__ esrc, const int* __restrict__ edst, int E,
    int* __restrict__ counts, int* __restrict__ buckets,
    int* __restrict__ ovcnt, int* __restrict__ ovd, int* __restrict__ ovs)
{
    int i = blockIdx.x * 256 + threadIdx.x;
    if (i >= E) return;
    int d = edst[i], s = esrc[i];
    int c = atomicAdd(&counts[(size_t)d * CSTRIDE], 1);
    if (c < BCAP) buckets[(size_t)d * BCAP + c] = s;
    else { int o = atomicAdd(ovcnt, 1); if (o < OVCAP) { ovd[o] = d; ovs[o] = s; } }
}

__global__ __launch_bounds__(256) void aggregate_kernel_f32(
    const float* __restrict__ H,
    const int* __restrict__ buckets, const int* __restrict__ counts,
    const int* __restrict__ ovcnt, const int* __restrict__ ovd,
    const int* __restrict__ ovs, unsigned short* __restrict__ aggb, int n_dst)
{
    int dst = blockIdx.x * 4 + (threadIdx.x >> 6);
    if (dst >= n_dst) return;
    int lane = threadIdx.x & 63;
    int dg = counts[(size_t)dst * CSTRIDE];
    int m = dg < BCAP ? dg : BCAP;
    int nov = *ovcnt; if (nov > OVCAP) nov = OVCAP;
    int idx = (lane < m) ? buckets[(size_t)dst * BCAP + lane] : 0;

    const int hl = lane & 31, half = lane >> 5;
    const float4* H4 = (const float4*)H;
    float acc[4] = {0, 0, 0, 0};
    int j = 0;
    for (; j + 4 <= m; j += 4) {
        int sA = __shfl(idx, j + half);
        int sB = __shfl(idx, j + 2 + half);
        float4 va = H4[(size_t)sA * 32 + hl];
        float4 vb = H4[(size_t)sB * 32 + hl];
        acc[0] += va.x + vb.x; acc[1] += va.y + vb.y;
        acc[2] += va.z + vb.z; acc[3] += va.w + vb.w;
    }
    for (; j < m; j += 2) {
        int jj = j + half;
        int s = __shfl(idx, jj < m ? jj : m - 1);
        float4 v = H4[(size_t)s * 32 + hl];
        float w = (jj < m) ? 1.f : 0.f;
        acc[0] += w * v.x; acc[1] += w * v.y;
        acc[2] += w * v.z; acc[3] += w * v.w;
    }
    for (int k = half; k < nov; k += 2) {
        if (ovd[k] == dst) {
            float4 v = H4[(size_t)ovs[k] * 32 + hl];
            acc[0] += v.x; acc[1] += v.y; acc[2] += v.z; acc[3] += v.w;
        }
    }
#pragma unroll
    for (int k = 0; k < 4; ++k) acc[k] += __shfl_xor(acc[k], 32);
    if (half == 0) {
        uint2 o;
        o.x = (unsigned)f2bf(acc[0]) | ((unsigned)f2bf(acc[1]) << 16);
        o.y = (unsigned)f2bf(acc[2]) | ((unsigned)f2bf(acc[3]) << 16);
        ((uint2*)aggb)[(size_t)dst * 32 + hl] = o;
    }
}

__global__ __launch_bounds__(256) void gemm_finalize_kernel(
    const unsigned short* __restrict__ aggb, const unsigned short* __restrict__ Wt,
    const float* __restrict__ b, const int* __restrict__ counts,
    float* __restrict__ out, int n_dst)
{
    __shared__ __align__(16) unsigned char smem[52224];
    unsigned short* Ash = (unsigned short*)smem;                   // [64][LDA]
    unsigned short* Wsh = (unsigned short*)(smem + 64 * LDA * 2);  // [128][LDA]
    float* Csh = (float*)smem;                                     // [64][132]

    const int tid  = threadIdx.x;
    const int lane = tid & 63, wv = tid >> 6;
    const size_t row0 = (size_t)blockIdx.x * 64;

#pragma unroll
    for (int t = 0; t < 4; ++t) {
        int i = tid + t * 256;
        int r = i >> 4, k8 = (i & 15) << 3;
        size_t gr = row0 + r;
        uint4 v = (gr < (size_t)n_dst) ? ((const uint4*)aggb)[gr * 16 + (i & 15)]
                                       : make_uint4(0, 0, 0, 0);
        *(uint4*)&Ash[r * LDA + k8] = v;
    }
#pragma unroll
    for (int t = 0; t < 8; ++t) {
        int i = tid + t * 256;
        int n = i >> 4, k8 = (i & 15) << 3;
        *(uint4*)&Wsh[n * LDA + k8] = ((const uint4*)Wt)[i];
    }
    __syncthreads();

    const int m0 = wv * 16;
    const int fl = lane & 15, quad = lane >> 4;

    f32x4 cacc[8];
#pragma unroll
    for (int n = 0; n < 8; ++n) cacc[n] = (f32x4){0.f, 0.f, 0.f, 0.f};

#pragma unroll
    for (int kc = 0; kc < 128; kc += 32) {
        bf16x8 a = *(const bf16x8*)&Ash[(m0 + fl) * LDA + kc + quad * 8];
#pragma unroll
        for (int n = 0; n < 8; ++n) {
            bf16x8 bf = *(const bf16x8*)&Wsh[(n * 16 + fl) * LDA + kc + quad * 8];
            cacc[n] = __builtin_amdgcn_mfma_f32_16x16x32_bf16(a, bf, cacc[n], 0, 0, 0);
        }
    }

    float inv[4], gate[4];
#pragma unroll
    for (int r = 0; r < 4; ++r) {
        size_t gr = row0 + m0 + quad * 4 + r;
        int dg = (gr < (size_t)n_dst) ? counts[gr * CSTRIDE] : 0;
        inv[r]  = 1.0f / (float)(dg > 1 ? dg : 1);
        gate[r] = (dg > 0) ? 1.0f : 0.0f;
    }
    __syncthreads();   // Ash/Wsh dead; reuse as Csh

#pragma unroll
    for (int n = 0; n < 8; ++n) {
        int col = n * 16 + fl;
        float bc = b[col];
#pragma unroll
        for (int r = 0; r < 4; ++r) {
            float v = cacc[n][r] * inv[r] + bc * gate[r];
            Csh[(m0 + quad * 4 + r) * 132 + col] = fmaxf(v, 0.0f);
        }
    }
    __syncthreads();

#pragma unroll
    for (int t = 0; t < 8; ++t) {
        int i = tid + t * 256;
        int rr = i >> 5, c4 = i & 31;
        size_t gr = row0 + rr;
        if (gr < (size_t)n_dst) {
            f32x4 vout = *(f32x4*)&Csh[rr * 132 + c4 * 4];
            __builtin_nontemporal_store(vout, (f32x4*)out + gr * (D / 4) + c4);
        }
    }
}

extern "C" void kernel_launch(void* const* d_in, const int* in_sizes, int n_in,
                              void* d_out, int out_size, void* d_ws, size_t ws_size,
                              hipStream_t stream) {
    const float* H    = (const float*)d_in[0];   // [N_src, 128]
    const float* W    = (const float*)d_in[1];   // [128, 128]
    const float* b    = (const float*)d_in[2];   // [128]
    const int*   esrc = (const int*)d_in[3];     // [E]
    const int*   edst = (const int*)d_in[4];     // [E]
    const int    E     = in_sizes[3];
    const int    n_dst = out_size / D;
    const int    nsrc_elems = in_sizes[0];       // N_src * 128
    const int    n_src = nsrc_elems / D;

    float* out = (float*)d_out;

    // ws: Wt | counts(padded) | ovcnt(pad) | ovd | ovs | buckets | aggb | WHb
    char* p = (char*)d_ws;
    unsigned short* Wt = (unsigned short*)p;  p += 128 * 128 * sizeof(unsigned short);
    int* counts = (int*)p;  p += (size_t)n_dst * CSTRIDE * 4;
    int* ovcnt  = (int*)p;  p += 256;            // zeroed together with counts
    int* ovd    = (int*)p;  p += (size_t)OVCAP * 4;
    int* ovs    = (int*)p;  p += (size_t)OVCAP * 4;
    int* buckets= (int*)p;  p += (size_t)n_dst * BCAP * 4;
    size_t agg_off = (((size_t)(p - (char*)d_ws)) + 255) & ~(size_t)255;
    unsigned short* aggb = (unsigned short*)((char*)d_ws + agg_off);
    size_t wh_off = (agg_off + (size_t)n_dst * D * 2 + 255) & ~(size_t)255;
    bool use_wh = (ws_size >= wh_off + (size_t)nsrc_elems * 2);
    unsigned short* WHb = (unsigned short*)((char*)d_ws + wh_off);

    // Zero counts+ovcnt AND transpose W->Wt bf16 in one dispatch.
    int nz4 = (n_dst * CSTRIDE + 64) / 4;
    int gz = nz4 > 8192 ? nz4 : 8192;
    zero_wt_kernel<<<(gz + 255) / 256, 256, 0, stream>>>(W, Wt, counts, nz4);

    if (use_wh) {
        int G = (n_src + 63) / 64;
        int Ge = (E + 511) / 512;
        if (Ge > G) G = Ge;
        prep_gemm_kernel<<<G, 256, 0, stream>>>(
            H, n_src, Wt, WHb, esrc, edst, E, counts, buckets, ovcnt, ovd, ovs);
        agg_finalize_kernel<<<(n_dst + 3) / 4, 256, 0, stream>>>(
            (const uint4*)WHb, buckets, counts, ovcnt, ovd, ovs, b, out, n_dst);
    } else {
        prep_fb_kernel<<<(E + 255) / 256, 256, 0, stream>>>(
            esrc, edst, E, counts, buckets, ovcnt, ovd, ovs);
        aggregate_kernel_f32<<<(n_dst + 3) / 4, 256, 0, stream>>>(
            H, buckets, counts, ovcnt, ovd, ovs, aggb, n_dst);
        gemm_finalize_kernel<<<(n_dst + 63) / 64, 256, 0, stream>>>(
            aggb, Wt, b, counts, out, n_dst);
    }
}